// Round 4
// baseline (373.864 us; speedup 1.0000x reference)
//
#include <hip/hip_runtime.h>
#include <hip/hip_bf16.h>

#define LEAKY_ALPHA 0.3f
#define EPS 1e-6f

// Problem constants (from reference setup_inputs):
// B=8, N=8192, C=256, H=256, O=256, K=64
#define B_SZ 8
#define N_SZ 8192
#define C_SZ 256
#define H_SZ 256
#define O_SZ 256
#define K_SZ 64

// neighbor_set may be int32 or int64. Detect at runtime: for int64 with
// values < 8192, every odd 32-bit word is 0. Probe only the first 64 int32
// words (256 B) so we never read past an int32 buffer.
__device__ __forceinline__ int detect_is64_wave0(const int* raw, int t, int* s_flag) {
    if (t < 64) {
        int v = (t < 32) ? raw[2 * t + 1] : 0;
        unsigned long long m = __ballot(v != 0);
        if (t == 0) *s_flag = (m == 0ULL) ? 1 : 0;
    }
    __syncthreads();
    return *s_flag;
}

__device__ __forceinline__ int load_nbr(const int* raw, int k, int is64) {
    return is64 ? raw[2 * k] : raw[k];   // little-endian low word
}

// Stage 1: ws[b][k][h] = w_k * leaky_relu(emb[b,nbr_k,:]·Qw[:,h] + Qb[h])
// grid (32, 8): blockIdx.x = k-group (2 k's each), blockIdx.y = b; 256 threads = h.
__global__ __launch_bounds__(256) void convolve_stage1(
    const float* __restrict__ emb,      // (B, N, C) fp32
    const float* __restrict__ weights,  // (N, N) fp32
    const float* __restrict__ Qw,       // (C, H) fp32
    const float* __restrict__ Qb,       // (H,) fp32
    const int* __restrict__ nbrs_raw,   // (K,) int32 or int64
    const int* __restrict__ node_raw,   // (1,)
    float* __restrict__ ws_out)         // (B, K, H) fp32 scratch
{
    const int t  = threadIdx.x;          // h
    const int kg = blockIdx.x;           // 0..31
    const int b  = blockIdx.y;           // 0..7
    const int k0 = kg * 2;

    __shared__ int s_is64;
    __shared__ float s_emb[2][C_SZ];

    const int is64 = detect_is64_wave0(nbrs_raw, t, &s_is64);
    const int node = node_raw[0];        // low word safe for both widths

    const int n0 = load_nbr(nbrs_raw, k0, is64);
    const int n1 = load_nbr(nbrs_raw, k0 + 1, is64);
    s_emb[0][t] = emb[((size_t)b * N_SZ + n0) * C_SZ + t];
    s_emb[1][t] = emb[((size_t)b * N_SZ + n1) * C_SZ + t];
    __syncthreads();

    const float w0 = weights[(size_t)n0 * N_SZ + node];
    const float w1 = weights[(size_t)n1 * N_SZ + node];

    const float qb = Qb[t];
    float acc0 = qb, acc1 = qb;
    #pragma unroll 8
    for (int c = 0; c < C_SZ; ++c) {
        const float qw = Qw[c * H_SZ + t];    // coalesced across lanes
        acc0 = fmaf(s_emb[0][c], qw, acc0);   // LDS broadcast reads
        acc1 = fmaf(s_emb[1][c], qw, acc1);
    }
    acc0 = acc0 >= 0.f ? acc0 : LEAKY_ALPHA * acc0;
    acc1 = acc1 >= 0.f ? acc1 : LEAKY_ALPHA * acc1;

    ws_out[((b * K_SZ + k0    ) << 8) + t] = w0 * acc0;
    ws_out[((b * K_SZ + k0 + 1) << 8) + t] = w1 * acc1;
}

// Stage 2: per b: reduce over k, concat with node embedding, (512->256) GEMV,
// leaky_relu, row-normalize, fp32 store. grid 8 blocks, 256 threads = o.
__global__ __launch_bounds__(256) void convolve_stage2(
    const float* __restrict__ emb,      // (B, N, C)
    const float* __restrict__ weights,  // (N, N)
    const float* __restrict__ Ww,       // (C+H, O)
    const float* __restrict__ Wb,       // (O,)
    const int* __restrict__ nbrs_raw,   // (K,)
    const int* __restrict__ node_raw,   // (1,)
    const float* __restrict__ ws_in,    // (B, K, H) fp32
    float* __restrict__ out)            // (B, O) fp32  <-- reference output dtype
{
    const int t = threadIdx.x;   // o (also h for the reduce phase)
    const int b = blockIdx.x;

    __shared__ int s_is64;
    __shared__ float s_cat[C_SZ + H_SZ];   // 512
    __shared__ float s_w[K_SZ];
    __shared__ float s_red[4];

    const int is64 = detect_is64_wave0(nbrs_raw, t, &s_is64);
    const int node = node_raw[0];

    if (t < K_SZ) {
        const int n = load_nbr(nbrs_raw, t, is64);
        s_w[t] = weights[(size_t)n * N_SZ + node];
    }

    // numerator: sum_k (w_k * hid[b][k][t])  (already weighted in stage 1)
    float num = 0.f;
    #pragma unroll
    for (int k = 0; k < K_SZ; ++k)
        num += ws_in[((b * K_SZ + k) << 8) + t];

    // node embedding -> first half of concat
    s_cat[t] = emb[((size_t)b * N_SZ + node) * C_SZ + t];
    __syncthreads();

    float wsum = 0.f;
    #pragma unroll
    for (int k = 0; k < K_SZ; ++k) wsum += s_w[k];

    s_cat[C_SZ + t] = num / (wsum + EPS);
    __syncthreads();

    // (512 -> 256) GEMV
    float acc = Wb[t];
    #pragma unroll 8
    for (int c = 0; c < C_SZ + H_SZ; ++c)
        acc = fmaf(s_cat[c], Ww[c * O_SZ + t], acc);   // coalesced across lanes

    float h = acc >= 0.f ? acc : LEAKY_ALPHA * acc;

    // row norm: sum of h^2 over all 256 threads
    float ss = h * h;
    #pragma unroll
    for (int off = 32; off > 0; off >>= 1)
        ss += __shfl_down(ss, off, 64);
    if ((t & 63) == 0) s_red[t >> 6] = ss;
    __syncthreads();
    const float total = s_red[0] + s_red[1] + s_red[2] + s_red[3];
    const float norm = sqrtf(total);

    out[b * O_SZ + t] = h / (norm + EPS);
}

extern "C" void kernel_launch(void* const* d_in, const int* in_sizes, int n_in,
                              void* d_out, int out_size, void* d_ws, size_t ws_size,
                              hipStream_t stream)
{
    const float* emb = (const float*)d_in[0];
    const float* wts = (const float*)d_in[1];
    const float* Qw  = (const float*)d_in[2];
    const float* Qb  = (const float*)d_in[3];
    const float* Ww  = (const float*)d_in[4];
    const float* Wb  = (const float*)d_in[5];
    const int* nbrs = (const int*)d_in[6];
    const int* node = (const int*)d_in[7];

    float* ws = (float*)d_ws;                    // needs 8*64*256*4 = 512 KB
    float* out = (float*)d_out;

    dim3 g1(32, 8);
    convolve_stage1<<<g1, 256, 0, stream>>>(emb, wts, Qw, Qb, nbrs, node, ws);
    convolve_stage2<<<8, 256, 0, stream>>>(emb, wts, Ww, Wb, nbrs, node, ws, out);
}

// Round 5
// 355.617 us; speedup vs baseline: 1.0513x; 1.0513x over previous
//
#include <hip/hip_runtime.h>
#include <hip/hip_bf16.h>

#define LEAKY_ALPHA 0.3f
#define EPS 1e-6f

// Problem constants (from reference setup_inputs):
// B=8, N=8192, C=256, H=256, O=256, K=64
#define B_SZ 8
#define N_SZ 8192
#define C_SZ 256
#define H_SZ 256
#define O_SZ 256
#define K_SZ 64

// neighbor_set may be int32 or int64. Detect at runtime: for int64 with
// values < 8192, every odd 32-bit word is 0. Probe only the first 64 int32
// words (256 B) so we never read past an int32 buffer.
__device__ __forceinline__ int detect_is64_wave0(const int* raw, int t, int* s_flag) {
    if (t < 64) {
        int v = (t < 32) ? raw[2 * t + 1] : 0;
        unsigned long long m = __ballot(v != 0);
        if (t == 0) *s_flag = (m == 0ULL) ? 1 : 0;
    }
    __syncthreads();
    return *s_flag;
}

__device__ __forceinline__ int load_nbr(const int* raw, int k, int is64) {
    return is64 ? raw[2 * k] : raw[k];   // little-endian low word
}

// Stage 1: ws[b][k][h] = w_k * leaky_relu(emb[b,nbr_k,:]·Qw[:,h] + Qb[h])
// grid (32, 8): blockIdx.x = k-group (2 k's each), blockIdx.y = b; 256 threads = h.
// 256 blocks spread over the GPU; latency-bound, ~3 us. Unchanged from R4 (passing).
__global__ __launch_bounds__(256) void convolve_stage1(
    const float* __restrict__ emb,      // (B, N, C) fp32
    const float* __restrict__ weights,  // (N, N) fp32
    const float* __restrict__ Qw,       // (C, H) fp32
    const float* __restrict__ Qb,       // (H,) fp32
    const int* __restrict__ nbrs_raw,   // (K,) int32 or int64
    const int* __restrict__ node_raw,   // (1,)
    float* __restrict__ ws_out)         // (B, K, H) fp32 scratch
{
    const int t  = threadIdx.x;          // h
    const int kg = blockIdx.x;           // 0..31
    const int b  = blockIdx.y;           // 0..7
    const int k0 = kg * 2;

    __shared__ int s_is64;
    __shared__ float s_emb[2][C_SZ];

    const int is64 = detect_is64_wave0(nbrs_raw, t, &s_is64);
    const int node = node_raw[0];        // low word safe for both widths

    const int n0 = load_nbr(nbrs_raw, k0, is64);
    const int n1 = load_nbr(nbrs_raw, k0 + 1, is64);
    s_emb[0][t] = emb[((size_t)b * N_SZ + n0) * C_SZ + t];
    s_emb[1][t] = emb[((size_t)b * N_SZ + n1) * C_SZ + t];
    __syncthreads();

    const float w0 = weights[(size_t)n0 * N_SZ + node];
    const float w1 = weights[(size_t)n1 * N_SZ + node];

    const float qb = Qb[t];
    float acc0 = qb, acc1 = qb;
    #pragma unroll 8
    for (int c = 0; c < C_SZ; ++c) {
        const float qw = Qw[c * H_SZ + t];    // coalesced across lanes
        acc0 = fmaf(s_emb[0][c], qw, acc0);   // LDS broadcast reads
        acc1 = fmaf(s_emb[1][c], qw, acc1);
    }
    acc0 = acc0 >= 0.f ? acc0 : LEAKY_ALPHA * acc0;
    acc1 = acc1 >= 0.f ? acc1 : LEAKY_ALPHA * acc1;

    ws_out[((b * K_SZ + k0    ) << 8) + t] = w0 * acc0;
    ws_out[((b * K_SZ + k0 + 1) << 8) + t] = w1 * acc1;
}

// Stage 2: per b: reduce over k, concat with node embedding, (512->256) GEMV,
// leaky_relu, row-normalize, fp32 store. grid 8 blocks, 256 threads.
// GEMV restructured: thread t -> (o_base = (t&63)*4, c-partition = t>>6).
// float4 Ww loads (16 B/lane, 1 KB/wave fully coalesced) cut VMEM instr 4x;
// s_cat[c] is wave-uniform within each c-partition (LDS broadcast).
__global__ __launch_bounds__(256) void convolve_stage2(
    const float* __restrict__ emb,      // (B, N, C)
    const float* __restrict__ weights,  // (N, N)
    const float* __restrict__ Ww,       // (C+H, O)
    const float* __restrict__ Wb,       // (O,)
    const int* __restrict__ nbrs_raw,   // (K,)
    const int* __restrict__ node_raw,   // (1,)
    const float* __restrict__ ws_in,    // (B, K, H) fp32
    float* __restrict__ out)            // (B, O) fp32
{
    const int t = threadIdx.x;
    const int b = blockIdx.x;

    __shared__ int s_is64;
    __shared__ float s_cat[C_SZ + H_SZ];     // 512
    __shared__ float s_w[K_SZ];
    __shared__ float s_part[4 * O_SZ];       // 4 c-partitions x 256 o
    __shared__ float s_red[4];

    const int is64 = detect_is64_wave0(nbrs_raw, t, &s_is64);
    const int node = node_raw[0];

    if (t < K_SZ) {
        const int n = load_nbr(nbrs_raw, t, is64);
        s_w[t] = weights[(size_t)n * N_SZ + node];
    }

    // numerator: sum_k (w_k * hid[b][k][t])  (already weighted in stage 1; L2-hot)
    float num = 0.f;
    #pragma unroll 8
    for (int k = 0; k < K_SZ; ++k)
        num += ws_in[((b * K_SZ + k) << 8) + t];

    // node embedding -> first half of concat
    s_cat[t] = emb[((size_t)b * N_SZ + node) * C_SZ + t];
    __syncthreads();

    float wsum = 0.f;
    #pragma unroll
    for (int k = 0; k < K_SZ; ++k) wsum += s_w[k];

    s_cat[C_SZ + t] = num / (wsum + EPS);
    __syncthreads();

    // (512 -> 256) GEMV, float4-coalesced.
    const int ob = (t & 63) << 2;   // output base: 0,4,...,252
    const int cg = t >> 6;          // c-partition 0..3 (wave-uniform)
    float4 acc = make_float4(0.f, 0.f, 0.f, 0.f);
    const int c0 = cg * 128;
    #pragma unroll 8
    for (int c = c0; c < c0 + 128; ++c) {
        const float sc = s_cat[c];                              // LDS broadcast
        const float4 w4 = *(const float4*)(Ww + c * O_SZ + ob); // 16 B/lane coalesced
        acc.x = fmaf(sc, w4.x, acc.x);
        acc.y = fmaf(sc, w4.y, acc.y);
        acc.z = fmaf(sc, w4.z, acc.z);
        acc.w = fmaf(sc, w4.w, acc.w);
    }
    *(float4*)&s_part[cg * O_SZ + ob] = acc;
    __syncthreads();

    // combine partitions: thread t owns output o = t
    float v = Wb[t] + s_part[t] + s_part[O_SZ + t]
                    + s_part[2 * O_SZ + t] + s_part[3 * O_SZ + t];
    float h = v >= 0.f ? v : LEAKY_ALPHA * v;

    // row norm: sum of h^2 over all 256 threads
    float ss = h * h;
    #pragma unroll
    for (int off = 32; off > 0; off >>= 1)
        ss += __shfl_down(ss, off, 64);
    if ((t & 63) == 0) s_red[t >> 6] = ss;
    __syncthreads();
    const float total = s_red[0] + s_red[1] + s_red[2] + s_red[3];
    const float norm = sqrtf(total);

    out[b * O_SZ + t] = h / (norm + EPS);
}

extern "C" void kernel_launch(void* const* d_in, const int* in_sizes, int n_in,
                              void* d_out, int out_size, void* d_ws, size_t ws_size,
                              hipStream_t stream)
{
    const float* emb = (const float*)d_in[0];
    const float* wts = (const float*)d_in[1];
    const float* Qw  = (const float*)d_in[2];
    const float* Qb  = (const float*)d_in[3];
    const float* Ww  = (const float*)d_in[4];
    const float* Wb  = (const float*)d_in[5];
    const int* nbrs = (const int*)d_in[6];
    const int* node = (const int*)d_in[7];

    float* ws = (float*)d_ws;                    // needs 8*64*256*4 = 512 KB
    float* out = (float*)d_out;

    dim3 g1(32, 8);
    convolve_stage1<<<g1, 256, 0, stream>>>(emb, wts, Qw, Qb, nbrs, node, ws);
    convolve_stage2<<<8, 256, 0, stream>>>(emb, wts, Ww, Wb, nbrs, node, ws, out);
}